// Round 6
// baseline (137.956 us; speedup 1.0000x reference)
//
#include <hip/hip_runtime.h>

// ---------------------------------------------------------------------------
// GeometricSuperpositionSearch (all fp32): the reference collapses to
//   new[b,n,l] = sum_j x[b,n,j] * comb[b][j^l] * sign(j^l, j)
// where comb[b] is a single 16-component multivector per batch:
//   comb[b][i] = sum_k weights[b,k] * scores[b,k] * (templates[k,i] + rule_mod[b,k,i])
//
// R10: delete k2 as a dispatch. The k2 chain (summary/MLP/gumbel/softmax ->
// comb[8][16]) is deterministic and tiny, so EVERY k3 block recomputes it
// from `partial` (64 KiB, L2/L3-broadcast) while its 16 KB cpu tile is in
// flight in registers. Bitwise-identical comb in all blocks; zero cross-block
// communication; graph = 2 kernels (k1 reduce -> k3 fused apply).
//  - cooperative sync: abandoned (R6 300us / R8 225us: grid.sync costs
//    ~100us/sync on 8-XCD MI355X regardless of spill)
//  - last-block atomic merge: blocked by workspace poisoning (counter not 0)
//  - k3 keeps R9's verified coalesced load -> swizzled LDS -> row compute ->
//    coalesced nontemporal store; K2 scratch and the tile share one LDS
//    buffer (K2 state is dead before the tile is written)
// RNG: jax partitionable threefry: counter (0, t), key (0, 42),
// bits = x0 ^ x1.  (Verified: absmax 3.9e-3.)
// ---------------------------------------------------------------------------

#define B_ 8
#define N_ 65536
#define D_ 16
#define K_ 8
#define M_ 8
#define HID_ 64
#define BLK_PER_B 128                    // k1 slabs per batch
#define ROWS_PER_BLK (N_ / BLK_PER_B)    // 512 rows -> 2048 float4 per slab

typedef float f4v __attribute__((ext_vector_type(4)));

// ---- compile-time Cayley sign table: SGN.v[a][b] = sign of e_a * e_b -> e_{a^b}
struct SgnTab { float v[16][16]; };
constexpr SgnTab make_sgn() {
  SgnTab t{};
  for (int a = 0; a < 16; a++)
    for (int b = 0; b < 16; b++) {
      float s = 1.0f;
      for (int i = 0; i < 4; i++)
        if ((b >> i) & 1) {
          int h = a >> (i + 1), pc = 0;
          for (int q = 0; q < 4; q++) pc += (h >> q) & 1;
          if (pc & 1) s = -s;
          if ((a >> i) & 1) s *= (i == 0 ? 0.0f : 1.0f);  // metric {0,1,1,1}
        }
      t.v[a][b] = s;
    }
  return t;
}
constexpr SgnTab SGN = make_sgn();

// ---- threefry2x32-20, exactly as in jax/_src/prng.py ----
__device__ __forceinline__ unsigned rotl32(unsigned x, int n) {
  return (x << n) | (x >> (32 - n));
}
__device__ void threefry2x32(unsigned k0, unsigned k1, unsigned& x0, unsigned& x1) {
  unsigned ks0 = k0, ks1 = k1, ks2 = k0 ^ k1 ^ 0x1BD11BDAu;
  x0 += ks0; x1 += ks1;
  const int rotA[4] = {13, 15, 26, 6};
  const int rotB[4] = {17, 29, 16, 24};
#define TF_R4(rot)                                      \
  _Pragma("unroll")                                     \
  for (int r = 0; r < 4; r++) {                         \
    x0 += x1; x1 = rotl32(x1, rot[r]); x1 ^= x0;        \
  }
  TF_R4(rotA); x0 += ks1; x1 += ks2 + 1u;
  TF_R4(rotB); x0 += ks2; x1 += ks0 + 2u;
  TF_R4(rotA); x0 += ks0; x1 += ks1 + 3u;
  TF_R4(rotB); x0 += ks1; x1 += ks2 + 4u;
  TF_R4(rotA); x0 += ks2; x1 += ks0 + 5u;
#undef TF_R4
}

__device__ __forceinline__ void apply_row(const float cb[16], const float x[16],
                                          float o[16]) {
#pragma unroll
  for (int l = 0; l < 16; l++) {
    float acc = 0.f;
#pragma unroll
    for (int j = 0; j < 16; j++) {
      const float s = SGN.v[j ^ l][j];                  // compile-time constant
      if (s > 0.5f)       acc = fmaf(cb[j ^ l], x[j], acc);
      else if (s < -0.5f) acc = fmaf(-cb[j ^ l], x[j], acc);
    }
    o[l] = acc;
  }
}

// ---------------------------------------------------------------------------
// K2 scratch (16.8 KB). In k3_fused this is overlaid with the 16 KB tile
// (K2 state dead before the tile is written).
// ---------------------------------------------------------------------------
struct K2Shared {
  float summary[8][16], rs[8][16], gn[8][5], h[8][64], sc[8][8];
  float instr[8][8][16], g64[64], wts[8][8];
  float redA[8][16][16];  // [b][seg][d]
  float comb[128];
};

// prelude + body = the full k2 chain; combout may be LDS (&S.comb[0]) or global
__device__ __forceinline__ void k2_prelude(K2Shared& S, int t,
                                           const float* __restrict__ rulemem) {
  if (t < 128) {
    const int bb = t >> 4, d = t & 15;
    float rsum = 0.f;
    for (int m = 0; m < M_; m++) rsum += rulemem[(bb * M_ + m) * 16 + d];
    S.rs[bb][d] = rsum * (1.0f / (float)M_);
  }
  if (t < 64) {   // partitionable threefry gumbel: counter (0, t), key (0, 42)
    unsigned x0 = 0u, x1 = (unsigned)t;
    threefry2x32(0u, 42u, x0, x1);
    unsigned bits = x0 ^ x1;
    float f01 = __uint_as_float((bits >> 9) | 0x3f800000u) - 1.0f;
    float u = fmaxf(1e-6f, f01 * (1.0f - 2e-6f) + 1e-6f);
    S.g64[t] = -logf(-logf(u));
  }
}

__device__ void k2_body(K2Shared& S, int t,
                        const float* __restrict__ partial,
                        const float* __restrict__ ctrl,
                        const float* __restrict__ templates,
                        const float* __restrict__ W1,
                        const float* __restrict__ b1,
                        const float* __restrict__ W2,
                        const float* __restrict__ b2,
                        const float* __restrict__ Wr,
                        const float* __restrict__ br,
                        const float* __restrict__ logt,
                        float* combout) {
  // A: reduce partial[8][128][16]. flat idx = c*256+t: b = c>>3, d = t&15.
  {
    float acc[8];
#pragma unroll
    for (int q = 0; q < 8; q++) acc[q] = 0.f;
#pragma unroll
    for (int c = 0; c < 64; c++)
      acc[c >> 3] += partial[c * 256 + t];   // 64 coalesced, independent loads
#pragma unroll
    for (int q = 0; q < 8; q++) S.redA[q][t >> 4][t & 15] = acc[q];
  }
  __syncthreads();
  if (t < 128) {
    const int bb = t >> 4, d = t & 15;
    float s = 0.f;
#pragma unroll
    for (int g = 0; g < 16; g++) s += S.redA[bb][g][d];
    S.summary[bb][d] = s * (1.0f / (float)N_);
  }
  __syncthreads();
  // B: grade norms
  if (t < 40) {
    const int bb = t / 5, g = t % 5;
    float s = 0.f;
    for (int d = 0; d < 16; d++)
      if (__popc(d) == g) { float v = S.summary[bb][d]; s += v * v; }
    S.gn[bb][g] = sqrtf(s + 1e-12f);
  }
  __syncthreads();
  // C1: hidden layer [8][64]
  for (int idx = t; idx < B_ * HID_; idx += 256) {
    const int bb = idx >> 6, j = idx & 63;
    float a = b1[j];
    for (int i = 0; i < 9; i++) {
      float in = (i < 5) ? S.gn[bb][i] : ctrl[bb * 4 + (i - 5)];
      a += in * W1[i * HID_ + j];
    }
    S.h[bb][j] = fmaxf(a, 0.f);
  }
  __syncthreads();
  // C2: scores [8][8]
  if (t < 64) {
    const int bb = t >> 3, k = t & 7;
    float a = b2[k];
    for (int j = 0; j < HID_; j++) a += S.h[bb][j] * W2[j * K_ + k];
    S.sc[bb][k] = a;
  }
  __syncthreads();
  // D: instructions [8][8][16] = scores * (templates + rule_mod)
  for (int idx = t; idx < B_ * K_ * 16; idx += 256) {
    const int bb = idx >> 7, k = (idx >> 4) & 7, d = idx & 15;
    float a = br[k * 16 + d];
    for (int j = 0; j < 16; j++) a += S.rs[bb][j] * Wr[j * 128 + k * 16 + d];
    S.instr[bb][k][d] = S.sc[bb][k] * (templates[k * 16 + d] + a);
  }
  // weights: softmax((scores+g)/tau)
  if (t < 8) {
    float lt = logt[0];
    float tau = fminf(fmaxf(expf(lt), 0.1f), 5.0f);
    float z[8], m = -1e30f;
    for (int k = 0; k < 8; k++) {
      z[k] = (S.sc[t][k] + S.g64[t * 8 + k]) / tau;
      m = fmaxf(m, z[k]);
    }
    float ssum = 0.f;
    for (int k = 0; k < 8; k++) { z[k] = expf(z[k] - m); ssum += z[k]; }
    for (int k = 0; k < 8; k++) S.wts[t][k] = z[k] / ssum;
  }
  __syncthreads();
  // F: comb[b][i] = sum_k w * instr
  if (t < 128) {
    const int bb = t >> 4, i = t & 15;
    float s = 0.f;
    for (int k = 0; k < 8; k++) s += S.wts[bb][k] * S.instr[bb][k][i];
    combout[bb * 16 + i] = s;
  }
}

// ---------------------------------------------------------------------------
// k1: per-(b,d) partial sums of cpu_state over a 512-row slab.
// grid (BLK_PER_B, B_) = 1024 blocks, 256 threads. Fully coalesced loads.
// ---------------------------------------------------------------------------
__global__ __launch_bounds__(256) void k1_reduce(
    const float* __restrict__ cpu, float* __restrict__ partial) {
  const int b = blockIdx.y, blk = blockIdx.x, t = threadIdx.x;
  const float4* base =
      (const float4*)(cpu + (((size_t)b << 16) + (size_t)blk * ROWS_PER_BLK) * D_);
  float a0 = 0.f, a1 = 0.f, a2 = 0.f, a3 = 0.f;
#pragma unroll
  for (int i = 0; i < (ROWS_PER_BLK * 4) / 256; i++) {   // 8 iters
    float4 v = base[i * 256 + t];
    a0 += v.x; a1 += v.y; a2 += v.z; a3 += v.w;
  }
  __shared__ float red[256 * 4];
  red[t * 4 + 0] = a0; red[t * 4 + 1] = a1;
  red[t * 4 + 2] = a2; red[t * 4 + 3] = a3;
  __syncthreads();
  if (t < 16) {
    const int c = t >> 2, j = t & 3;      // component d = 4c + j = t
    float s = 0.f;
#pragma unroll
    for (int m = 0; m < 64; m++) s += red[(c + 4 * m) * 4 + j];
    partial[((size_t)b * BLK_PER_B + blk) * 16 + t] = s;
  }
}

// ---------------------------------------------------------------------------
// k3_fused (R10): redundant k2 chain + R9's coalesced apply, one kernel.
// grid 2048 blocks x 256 threads; each block owns a 256-row tile.
//   0. issue tile loads (16 float4/thread... 4) into registers  (in flight)
//   1. k2 chain from partial -> S.comb (identical in every block)
//   2. cb regs <- S.comb; K2 LDS dies; tile regs -> swizzled LDS
//   3. per-thread row from LDS (b128 bank floor), apply_row, write back
//   4. coalesced nontemporal stores
// swizzle: slot(r,w) = r*4 + (w ^ (r&3) ^ ((r>>2)&3))  (bijective per quad)
// ---------------------------------------------------------------------------
__global__ __launch_bounds__(256) void k3_fused(
    const float* __restrict__ cpu,
    const float* __restrict__ partial,
    const float* __restrict__ ctrl,
    const float* __restrict__ rulemem,
    const float* __restrict__ templates,
    const float* __restrict__ W1, const float* __restrict__ b1,
    const float* __restrict__ W2, const float* __restrict__ b2,
    const float* __restrict__ Wr, const float* __restrict__ br,
    const float* __restrict__ logt,
    float* __restrict__ out) {
  const int t = threadIdx.x;
  const int b = blockIdx.x >> 8;                    // 256 blocks per batch
  const size_t base4 = (size_t)blockIdx.x * 1024;   // float4 idx of tile start

  __shared__ __align__(16) char ubuf[sizeof(K2Shared)];  // 16.8 KB, overlays tile
  K2Shared& S = *(K2Shared*)ubuf;
  float4* lds4 = (float4*)ubuf;                     // 16 KB tile view

  const float4* in4 = (const float4*)cpu + base4;
  float4* out4 = (float4*)out + base4;

  // 0. issue tile loads into registers (overlap the k2 chain below)
  float4 r0 = in4[0 * 256 + t];
  float4 r1 = in4[1 * 256 + t];
  float4 r2 = in4[2 * 256 + t];
  float4 r3 = in4[3 * 256 + t];

  // 1. redundant k2 chain (deterministic -> identical comb in every block)
  k2_prelude(S, t, rulemem);
  k2_body(S, t, partial, ctrl, templates, W1, b1, W2, b2, Wr, br, logt,
          &S.comb[0]);
  __syncthreads();                                  // S.comb ready

  // 2. extract cb, then retire K2 state before overwriting LDS with the tile
  float cb[16];
#pragma unroll
  for (int i = 0; i < 16; i++) cb[i] = S.comb[b * 16 + i];
  __syncthreads();                                  // all reads of S done

  const int sw = ((t >> 2) & 3) ^ ((t >> 4) & 3);   // linear-phase swizzle
  lds4[(0 * 256 + t) ^ sw] = r0;
  lds4[(1 * 256 + t) ^ sw] = r1;
  lds4[(2 * 256 + t) ^ sw] = r2;
  lds4[(3 * 256 + t) ^ sw] = r3;
  __syncthreads();

  // 3. own row t from LDS, compute, write back in place
  {
    const int rsw = (t & 3) ^ ((t >> 2) & 3);
    float4 q0 = lds4[t * 4 + (0 ^ rsw)];
    float4 q1 = lds4[t * 4 + (1 ^ rsw)];
    float4 q2 = lds4[t * 4 + (2 ^ rsw)];
    float4 q3 = lds4[t * 4 + (3 ^ rsw)];
    float x[16] = {q0.x, q0.y, q0.z, q0.w, q1.x, q1.y, q1.z, q1.w,
                   q2.x, q2.y, q2.z, q2.w, q3.x, q3.y, q3.z, q3.w};
    float o[16];
    apply_row(cb, x, o);
    lds4[t * 4 + (0 ^ rsw)] = make_float4(o[0],  o[1],  o[2],  o[3]);
    lds4[t * 4 + (1 ^ rsw)] = make_float4(o[4],  o[5],  o[6],  o[7]);
    lds4[t * 4 + (2 ^ rsw)] = make_float4(o[8],  o[9],  o[10], o[11]);
    lds4[t * 4 + (3 ^ rsw)] = make_float4(o[12], o[13], o[14], o[15]);
  }
  __syncthreads();

  // 4. swizzled LDS -> coalesced nontemporal store (out is never re-read)
#pragma unroll
  for (int i = 0; i < 4; i++) {
    const int m = i * 256 + t;
    f4v v = *(const f4v*)&lds4[m ^ sw];
    __builtin_nontemporal_store(v, (f4v*)&out4[m]);
  }
}

// ---------------------------------------------------------------------------
// Fallback (tiny-workspace) path: R9's verified 3-kernel structure.
// ---------------------------------------------------------------------------
__global__ __launch_bounds__(256) void k2_small(
    const float* __restrict__ partial, const float* __restrict__ ctrl,
    const float* __restrict__ rulemem, const float* __restrict__ templates,
    const float* __restrict__ W1, const float* __restrict__ b1,
    const float* __restrict__ W2, const float* __restrict__ b2,
    const float* __restrict__ Wr, const float* __restrict__ br,
    const float* __restrict__ logt, float* __restrict__ comb) {
  const int t = threadIdx.x;
  __shared__ K2Shared S;
  k2_prelude(S, t, rulemem);
  k2_body(S, t, partial, ctrl, templates, W1, b1, W2, b2, Wr, br, logt, comb);
}

__global__ __launch_bounds__(256) void k3_apply_g(
    const float* __restrict__ cpu, const float* __restrict__ comb,
    float* __restrict__ out) {
  const int t = threadIdx.x;
  const int b = blockIdx.x >> 8;
  const size_t base4 = (size_t)blockIdx.x * 1024;
  __shared__ float4 lds4[1024];

  float cb[16];
  {
    const float* cp = comb + b * 16;
#pragma unroll
    for (int i = 0; i < 16; i++) cb[i] = cp[i];
  }
  const float4* in4 = (const float4*)cpu + base4;
  float4* out4 = (float4*)out + base4;
  const int sw = ((t >> 2) & 3) ^ ((t >> 4) & 3);
#pragma unroll
  for (int i = 0; i < 4; i++) {
    const int m = i * 256 + t;
    lds4[m ^ sw] = in4[m];
  }
  __syncthreads();
  {
    const int rsw = (t & 3) ^ ((t >> 2) & 3);
    float4 q0 = lds4[t * 4 + (0 ^ rsw)];
    float4 q1 = lds4[t * 4 + (1 ^ rsw)];
    float4 q2 = lds4[t * 4 + (2 ^ rsw)];
    float4 q3 = lds4[t * 4 + (3 ^ rsw)];
    float x[16] = {q0.x, q0.y, q0.z, q0.w, q1.x, q1.y, q1.z, q1.w,
                   q2.x, q2.y, q2.z, q2.w, q3.x, q3.y, q3.z, q3.w};
    float o[16];
    apply_row(cb, x, o);
    lds4[t * 4 + (0 ^ rsw)] = make_float4(o[0],  o[1],  o[2],  o[3]);
    lds4[t * 4 + (1 ^ rsw)] = make_float4(o[4],  o[5],  o[6],  o[7]);
    lds4[t * 4 + (2 ^ rsw)] = make_float4(o[8],  o[9],  o[10], o[11]);
    lds4[t * 4 + (3 ^ rsw)] = make_float4(o[12], o[13], o[14], o[15]);
  }
  __syncthreads();
#pragma unroll
  for (int i = 0; i < 4; i++) {
    const int m = i * 256 + t;
    f4v v = *(const f4v*)&lds4[m ^ sw];
    __builtin_nontemporal_store(v, (f4v*)&out4[m]);
  }
}

extern "C" void kernel_launch(void* const* d_in, const int* in_sizes, int n_in,
                              void* d_out, int out_size, void* d_ws, size_t ws_size,
                              hipStream_t stream) {
  const float* cpu       = (const float*)d_in[0];
  const float* ctrl      = (const float*)d_in[1];
  const float* rulemem   = (const float*)d_in[2];
  const float* templates = (const float*)d_in[3];
  const float* W1        = (const float*)d_in[4];
  const float* b1        = (const float*)d_in[5];
  const float* W2        = (const float*)d_in[6];
  const float* b2        = (const float*)d_in[7];
  const float* Wr        = (const float*)d_in[8];
  const float* br        = (const float*)d_in[9];
  const float* logt      = (const float*)d_in[10];
  float* outp = (float*)d_out;

  float* partial = (float*)d_ws;                       // 8*128*16 floats
  const size_t need = (size_t)(B_ * BLK_PER_B * 16) * sizeof(float);

  if (ws_size >= need) {
    // R10 2-kernel path: k1 reduce -> k3 fused (redundant k2 per block)
    k1_reduce<<<dim3(BLK_PER_B, B_), 256, 0, stream>>>(cpu, partial);
    k3_fused<<<2048, 256, 0, stream>>>(cpu, partial, ctrl, rulemem, templates,
                                       W1, b1, W2, b2, Wr, br, logt, outp);
  } else {
    // tiny-ws fallback: R9's 3-kernel path (partial staged in out, fully
    // consumed by k2 before k3's first store; comb in ws)
    float* comb = (float*)d_ws;
    partial = outp;
    k1_reduce<<<dim3(BLK_PER_B, B_), 256, 0, stream>>>(cpu, partial);
    k2_small<<<1, 256, 0, stream>>>(partial, ctrl, rulemem, templates, W1, b1,
                                    W2, b2, Wr, br, logt, comb);
    k3_apply_g<<<2048, 256, 0, stream>>>(cpu, comb, outp);
  }
}